// Round 7
// baseline (68.047 us; speedup 1.0000x reference)
//
#include <hip/hip_runtime.h>

#define WIN    7
#define IMH    640
#define IMW    640
#define OHH    634            // IMH - WIN + 1
#define OWW    634
#define NB     64
#define NBANDS 16
#define BROWS  40             // 15*40 + 34 = 634 output rows
#define NCT    5              // column tiles of 128 output cols
#define NPART  (NB * NBANDS * NCT)   // 5120 partials

__device__ __forceinline__ float ssim_val(const float4& V, float C1, float C2,
                                          float inv_np, float covh) {
    float us  = V.x * inv_np, ud  = V.y * inv_np;
    float uss = V.z * inv_np, udd = V.w * inv_np;
    float p  = us * us, q = ud * ud;
    float pd = p - q,  ps = p + q;
    float A1 = fmaf(0.5f, pd, C1), B1 = fmaf(0.5f, ps, C1);
    float A2 = fmaf(covh, (uss - udd) - pd, C2);
    float B2 = fmaf(covh, (uss + udd) - ps, C2);
    return (A1 * A2) * __builtin_amdgcn_rcpf(B1 * B2);
}

// Branch-free band processing: NROWS known at compile time, so every row body
// is straightline code the scheduler can pipeline loads across (rule: guards
// around row bodies were serializing load->compute in r6).
template<int NROWS>
__device__ __forceinline__ double process_band(
    const float* __restrict__ Xp, const float* __restrict__ Yp,
    float C1, float C2, bool active)
{
    const float inv_np = 1.0f / 49.0f;
    const float covh   = (49.0f / 48.0f) * 0.5f;

    // 7-slot register ring of horizontal moment sums (Ss,Sd,Sss,Sdd) per col;
    // zero-init makes rows 0..5 a natural warm-up for the running V.
    float4 ring0[WIN], ring1[WIN];
    #pragma unroll
    for (int u = 0; u < WIN; ++u) {
        ring0[u] = make_float4(0.f, 0.f, 0.f, 0.f);
        ring1[u] = make_float4(0.f, 0.f, 0.f, 0.f);
    }
    float4 V0 = make_float4(0.f, 0.f, 0.f, 0.f);
    float4 V1 = make_float4(0.f, 0.f, 0.f, 0.f);

    double acc  = 0.0;
    float  esum = 0.f;

    // R: runtime row index; U: compile-time ring slot; DOSSIM: compile-time.
#define ROWBODY(R, U, DOSSIM) do {                                            \
    const size_t off = (size_t)(R) * IMW;                                     \
    const float4 xa = *(const float4*)(Xp + off);                             \
    const float4 xb = *(const float4*)(Xp + off + 4);                         \
    const float4 ya = *(const float4*)(Yp + off);                             \
    const float4 yb = *(const float4*)(Yp + off + 4);                         \
    const float4 sa = make_float4(xa.x+ya.x, xa.y+ya.y, xa.z+ya.z, xa.w+ya.w);\
    const float4 sb = make_float4(xb.x+yb.x, xb.y+yb.y, xb.z+yb.z, xb.w+yb.w);\
    const float4 da = make_float4(xa.x-ya.x, xa.y-ya.y, xa.z-ya.z, xa.w-ya.w);\
    const float4 db = make_float4(xb.x-yb.x, xb.y-yb.y, xb.z-yb.z, xb.w-yb.w);\
    const float hs0 = ((sa.x+sa.y)+(sa.z+sa.w)) + ((sb.x+sb.y)+sb.z);         \
    const float hs1 = (hs0 - sa.x) + sb.w;                                    \
    const float hd0 = ((da.x+da.y)+(da.z+da.w)) + ((db.x+db.y)+db.z);         \
    const float hd1 = (hd0 - da.x) + db.w;                                    \
    const float hss0 = fmaf(sa.x,sa.x, fmaf(sa.y,sa.y, fmaf(sa.z,sa.z,        \
                       fmaf(sa.w,sa.w, fmaf(sb.x,sb.x, fmaf(sb.y,sb.y,        \
                            sb.z*sb.z))))));                                  \
    const float hss1 = fmaf(sb.w,sb.w, hss0 - sa.x*sa.x);                     \
    const float hdd0 = fmaf(da.x,da.x, fmaf(da.y,da.y, fmaf(da.z,da.z,        \
                       fmaf(da.w,da.w, fmaf(db.x,db.x, fmaf(db.y,db.y,        \
                            db.z*db.z))))));                                  \
    const float hdd1 = fmaf(db.w,db.w, hdd0 - da.x*da.x);                     \
    V0.x += hs0  - ring0[U].x;  V0.y += hd0  - ring0[U].y;                    \
    V0.z += hss0 - ring0[U].z;  V0.w += hdd0 - ring0[U].w;                    \
    V1.x += hs1  - ring1[U].x;  V1.y += hd1  - ring1[U].y;                    \
    V1.z += hss1 - ring1[U].z;  V1.w += hdd1 - ring1[U].w;                    \
    ring0[U] = make_float4(hs0, hd0, hss0, hdd0);                             \
    ring1[U] = make_float4(hs1, hd1, hss1, hdd1);                            \
    if ((DOSSIM) && active) {                                                 \
        const float e0 = ssim_val(V0, C1, C2, inv_np, covh);                  \
        const float e1 = ssim_val(V1, C1, C2, inv_np, covh);                  \
        esum += e0 + e1;                                                      \
    }                                                                         \
} while (0)

    // chunk 0: warm-up rows 0..6 (first SSIM at row 6)
    ROWBODY(0, 0, false); ROWBODY(1, 1, false); ROWBODY(2, 2, false);
    ROWBODY(3, 3, false); ROWBODY(4, 4, false); ROWBODY(5, 5, false);
    ROWBODY(6, 6, true);
    acc += (double)esum;

    constexpr int NCH = NROWS / WIN;          // 6 (NROWS=46) / 5 (NROWS=40)
    #pragma unroll 1
    for (int ch = 1; ch < NCH; ++ch) {
        const int base = ch * WIN;
        esum = 0.f;
        ROWBODY(base + 0, 0, true); ROWBODY(base + 1, 1, true);
        ROWBODY(base + 2, 2, true); ROWBODY(base + 3, 3, true);
        ROWBODY(base + 4, 4, true); ROWBODY(base + 5, 5, true);
        ROWBODY(base + 6, 6, true);
        acc += (double)esum;
    }

    // epilogue rows NCH*7 .. NROWS-1 (ring slots 0..REM-1, compile-time)
    constexpr int REM = NROWS - NCH * WIN;    // 4 (46) / 5 (40)
    esum = 0.f;
    if constexpr (REM > 0) ROWBODY(NCH * WIN + 0, 0, true);
    if constexpr (REM > 1) ROWBODY(NCH * WIN + 1, 1, true);
    if constexpr (REM > 2) ROWBODY(NCH * WIN + 2, 2, true);
    if constexpr (REM > 3) ROWBODY(NCH * WIN + 3, 3, true);
    if constexpr (REM > 4) ROWBODY(NCH * WIN + 4, 4, true);
    if constexpr (REM > 5) ROWBODY(NCH * WIN + 5, 5, true);
    acc += (double)esum;

#undef ROWBODY
    return acc;
}

// One wave per block: no LDS, no barriers. Each lane owns 2 output cols.
__global__ __launch_bounds__(64, 4) void ssim_stream(
    const float* __restrict__ X, const float* __restrict__ Y,
    const float* __restrict__ dr, double* __restrict__ partial)
{
    const int lane = threadIdx.x;
    const int tile = blockIdx.x;          // 0..4 (128 output cols each)
    const int band = blockIdx.y;          // 0..15
    const int b    = blockIdx.z;          // image
    const int r0   = band * BROWS;

    const int  ocol   = tile * 128 + 2 * lane;          // first of 2 out cols
    const int  cbase  = min(ocol, IMW - 8);             // load cols cbase..cbase+7
    const bool active = (ocol <= OWW - 2);              // both cols valid

    const size_t ioff = (size_t)b * IMH * IMW + (size_t)r0 * IMW + cbase;
    const float* Xp = X + ioff;
    const float* Yp = Y + ioff;

    const float drv = dr[b];
    const float C1 = (0.01f * drv) * (0.01f * drv);
    const float C2 = (0.03f * drv) * (0.03f * drv);

    double acc;
    if (band < NBANDS - 1) {
        acc = process_band<BROWS + WIN - 1>(Xp, Yp, C1, C2, active);  // 46 rows
    } else {
        acc = process_band<IMH - (NBANDS - 1) * BROWS>(Xp, Yp, C1, C2, active); // 40
    }

    // ---- wave reduction (single wave; no LDS, no barrier) ----
    for (int off = 32; off > 0; off >>= 1)
        acc += __shfl_down(acc, off, 64);
    if (lane == 0) {
        partial[((size_t)b * NBANDS + band) * NCT + tile] = acc;
    }
}

__global__ __launch_bounds__(512) void ssim_reduce(
    const double* __restrict__ partial, int n2, float* __restrict__ out)
{
    const double2* p2 = (const double2*)partial;
    double acc = 0.0;
    for (int i = threadIdx.x; i < n2; i += 512) {
        double2 v = p2[i];
        acc += v.x + v.y;
    }
    for (int off = 32; off > 0; off >>= 1)
        acc += __shfl_down(acc, off, 64);
    __shared__ double sred[8];
    if ((threadIdx.x & 63) == 0) sred[threadIdx.x >> 6] = acc;
    __syncthreads();
    if (threadIdx.x == 0) {
        double t = 0.0;
        #pragma unroll
        for (int k = 0; k < 8; ++k) t += sred[k];
        double denom = (double)NB * (double)OHH * (double)OWW;
        out[0] = (float)(t / denom);
    }
}

extern "C" void kernel_launch(void* const* d_in, const int* in_sizes, int n_in,
                              void* d_out, int out_size, void* d_ws, size_t ws_size,
                              hipStream_t stream) {
    const float* X  = (const float*)d_in[0];
    const float* Y  = (const float*)d_in[1];
    const float* dr = (const float*)d_in[2];
    // d_in[3] is w = ones/49; constant-folded in-kernel.
    double* partial = (double*)d_ws;   // 5120 * 8 B = 40 KB scratch

    dim3 grid(NCT, NBANDS, NB);
    ssim_stream<<<grid, 64, 0, stream>>>(X, Y, dr, partial);
    ssim_reduce<<<1, 512, 0, stream>>>(partial, NPART / 2, (float*)d_out);
}

// Round 8
// 60.945 us; speedup vs baseline: 1.1165x; 1.1165x over previous
//
#include <hip/hip_runtime.h>

#define WIN    7
#define IMH    640
#define IMW    640
#define OHH    634            // IMH - WIN + 1
#define OWW    634
#define NB     64
#define NBANDS 32
#define BROWS  20             // 31*20 + 14 = 634 output rows
#define NCT    5              // column tiles of 128 output cols
#define NTASK  (NB * NBANDS * NCT)   // 10240 wave-tasks
#define WPB    8              // waves per block (512 threads)
#define NBLK   (NTASK / WPB)  // 1280 blocks -> 1280 partials

__device__ __forceinline__ float ssim_val(const float4& V, float C1, float C2,
                                          float inv_np, float covh) {
    float us  = V.x * inv_np, ud  = V.y * inv_np;
    float uss = V.z * inv_np, udd = V.w * inv_np;
    float p  = us * us, q = ud * ud;
    float pd = p - q,  ps = p + q;
    float A1 = fmaf(0.5f, pd, C1), B1 = fmaf(0.5f, ps, C1);
    float A2 = fmaf(covh, (uss - udd) - pd, C2);
    float B2 = fmaf(covh, (uss + udd) - ps, C2);
    return (A1 * A2) * __builtin_amdgcn_rcpf(B1 * B2);
}

// 8 fully-independent waves per block (r6's proven per-wave loop, unchanged);
// the only inter-wave interaction is the final 8-double LDS reduce.
__global__ __launch_bounds__(512, 4) void ssim_stream(
    const float* __restrict__ X, const float* __restrict__ Y,
    const float* __restrict__ dr, double* __restrict__ partial)
{
    __shared__ double sred[WPB];

    const int tid  = threadIdx.x;
    const int lane = tid & 63;
    const int wv   = tid >> 6;

    const int task = blockIdx.x * WPB + wv;   // 0..10239
    const int tile = task % NCT;
    const int band = (task / NCT) % NBANDS;
    const int b    = task / (NCT * NBANDS);

    const int r0    = band * BROWS;
    const int nrows = min(BROWS + WIN - 1, IMH - r0);   // 26; last band 20

    const int  ocol   = tile * 128 + 2 * lane;          // first of 2 out cols
    const int  cbase  = min(ocol, IMW - 8);             // load cols cbase..cbase+7
    const bool active = (ocol <= OWW - 2);              // both cols valid

    const size_t ioff = (size_t)b * IMH * IMW + (size_t)r0 * IMW + cbase;
    const float* Xp = X + ioff;
    const float* Yp = Y + ioff;

    const float drv = dr[b];
    const float C1 = (0.01f * drv) * (0.01f * drv);
    const float C2 = (0.03f * drv) * (0.03f * drv);
    const float inv_np = 1.0f / 49.0f;
    const float covh   = (49.0f / 48.0f) * 0.5f;

    // 7-slot register ring of horizontal moment sums (Ss,Sd,Sss,Sdd) per col;
    // zero-init makes rows 0..5 a natural warm-up for the running V.
    float4 ring0[WIN], ring1[WIN];
    #pragma unroll
    for (int u = 0; u < WIN; ++u) {
        ring0[u] = make_float4(0.f, 0.f, 0.f, 0.f);
        ring1[u] = make_float4(0.f, 0.f, 0.f, 0.f);
    }
    float4 V0 = make_float4(0.f, 0.f, 0.f, 0.f);
    float4 V1 = make_float4(0.f, 0.f, 0.f, 0.f);

    double acc = 0.0;

    // rows unrolled by 7 so ring slot == u is compile-time (rule #20).
    for (int ch = 0; ch < 4; ++ch) {
        const int base = ch * WIN;
        float esum = 0.f;
        #pragma unroll
        for (int u = 0; u < WIN; ++u) {
            const int ur = base + u;
            if (ur < nrows) {                       // wave-uniform branch
                const size_t off = (size_t)ur * IMW;
                const float4 xa = *(const float4*)(Xp + off);
                const float4 xb = *(const float4*)(Xp + off + 4);
                const float4 ya = *(const float4*)(Yp + off);
                const float4 yb = *(const float4*)(Yp + off + 4);

                const float4 sa = make_float4(xa.x + ya.x, xa.y + ya.y,
                                              xa.z + ya.z, xa.w + ya.w);
                const float4 sb = make_float4(xb.x + yb.x, xb.y + yb.y,
                                              xb.z + yb.z, xb.w + yb.w);
                const float4 da = make_float4(xa.x - ya.x, xa.y - ya.y,
                                              xa.z - ya.z, xa.w - ya.w);
                const float4 db = make_float4(xb.x - yb.x, xb.y - yb.y,
                                              xb.z - yb.z, xb.w - yb.w);

                // horizontal 7-tap sums for the two output cols
                const float hs0 = ((sa.x + sa.y) + (sa.z + sa.w))
                                + ((sb.x + sb.y) + sb.z);
                const float hs1 = (hs0 - sa.x) + sb.w;
                const float hd0 = ((da.x + da.y) + (da.z + da.w))
                                + ((db.x + db.y) + db.z);
                const float hd1 = (hd0 - da.x) + db.w;
                const float hss0 = fmaf(sa.x, sa.x, fmaf(sa.y, sa.y,
                                   fmaf(sa.z, sa.z, fmaf(sa.w, sa.w,
                                   fmaf(sb.x, sb.x, fmaf(sb.y, sb.y,
                                        sb.z * sb.z))))));
                const float hss1 = fmaf(sb.w, sb.w, hss0 - sa.x * sa.x);
                const float hdd0 = fmaf(da.x, da.x, fmaf(da.y, da.y,
                                   fmaf(da.z, da.z, fmaf(da.w, da.w,
                                   fmaf(db.x, db.x, fmaf(db.y, db.y,
                                        db.z * db.z))))));
                const float hdd1 = fmaf(db.w, db.w, hdd0 - da.x * da.x);

                // running vertical sums: V += h_new - h[row-7] (ring slot u)
                V0.x += hs0  - ring0[u].x;  V0.y += hd0  - ring0[u].y;
                V0.z += hss0 - ring0[u].z;  V0.w += hdd0 - ring0[u].w;
                V1.x += hs1  - ring1[u].x;  V1.y += hd1  - ring1[u].y;
                V1.z += hss1 - ring1[u].z;  V1.w += hdd1 - ring1[u].w;
                ring0[u] = make_float4(hs0, hd0, hss0, hdd0);
                ring1[u] = make_float4(hs1, hd1, hss1, hdd1);

                if (active && ur >= WIN - 1) {
                    const float e0 = ssim_val(V0, C1, C2, inv_np, covh);
                    const float e1 = ssim_val(V1, C1, C2, inv_np, covh);
                    esum += e0 + e1;
                }
            }
        }
        acc += (double)esum;
    }

    // ---- wave reduction, then one 8-double block reduce ----
    for (int off = 32; off > 0; off >>= 1)
        acc += __shfl_down(acc, off, 64);
    if (lane == 0) sred[wv] = acc;
    __syncthreads();
    if (tid == 0) {
        double t = 0.0;
        #pragma unroll
        for (int k = 0; k < WPB; ++k) t += sred[k];
        partial[blockIdx.x] = t;
    }
}

__global__ __launch_bounds__(512) void ssim_reduce(
    const double* __restrict__ partial, int n2, float* __restrict__ out)
{
    const double2* p2 = (const double2*)partial;
    double acc = 0.0;
    for (int i = threadIdx.x; i < n2; i += 512) {
        double2 v = p2[i];
        acc += v.x + v.y;
    }
    for (int off = 32; off > 0; off >>= 1)
        acc += __shfl_down(acc, off, 64);
    __shared__ double sred[8];
    if ((threadIdx.x & 63) == 0) sred[threadIdx.x >> 6] = acc;
    __syncthreads();
    if (threadIdx.x == 0) {
        double t = 0.0;
        #pragma unroll
        for (int k = 0; k < 8; ++k) t += sred[k];
        double denom = (double)NB * (double)OHH * (double)OWW;
        out[0] = (float)(t / denom);
    }
}

extern "C" void kernel_launch(void* const* d_in, const int* in_sizes, int n_in,
                              void* d_out, int out_size, void* d_ws, size_t ws_size,
                              hipStream_t stream) {
    const float* X  = (const float*)d_in[0];
    const float* Y  = (const float*)d_in[1];
    const float* dr = (const float*)d_in[2];
    // d_in[3] is w = ones/49; constant-folded in-kernel.
    double* partial = (double*)d_ws;   // 1280 * 8 B = 10 KB scratch

    ssim_stream<<<NBLK, 512, 0, stream>>>(X, Y, dr, partial);
    ssim_reduce<<<1, 512, 0, stream>>>(partial, NBLK / 2, (float*)d_out);
}

// Round 9
// 56.498 us; speedup vs baseline: 1.2044x; 1.0787x over previous
//
#include <hip/hip_runtime.h>

#define WIN    7
#define IMH    640
#define IMW    640
#define OHH    634            // IMH - WIN + 1
#define OWW    634
#define NB     64
#define NBANDS 32
#define BROWS  20             // 31*20 + 14 = 634 output rows
#define NCT    5              // column tiles of 128 output cols
#define NTASK  (NB * NBANDS * NCT)   // 10240 wave-tasks
#define WPB    4              // waves per block (256 threads)
#define NBLK   (NTASK / WPB)  // 2560 blocks -> 2560 partials

__device__ __forceinline__ float ssim_val(const float4& V, float C1, float C2,
                                          float inv_np, float covh) {
    float us  = V.x * inv_np, ud  = V.y * inv_np;
    float uss = V.z * inv_np, udd = V.w * inv_np;
    float p  = us * us, q = ud * ud;
    float pd = p - q,  ps = p + q;
    float A1 = fmaf(0.5f, pd, C1), B1 = fmaf(0.5f, ps, C1);
    float A2 = fmaf(covh, (uss - udd) - pd, C2);
    float B2 = fmaf(covh, (uss + udd) - ps, C2);
    return (A1 * A2) * __builtin_amdgcn_rcpf(B1 * B2);
}

// Fully-unrolled band loop with 1-row register prefetch. NROWS is
// compile-time, so parity (u&1), ring slot (u%7) and DOSSIM are all static
// (rule #20). Prefetch of row u+1 is issued BEFORE row u's compute, so each
// iteration's vmcnt wait overlaps the previous row's ~190cy of VALU work.
template<int NROWS>
__device__ double band_loop(const float* __restrict__ Xp,
                            const float* __restrict__ Yp,
                            float C1, float C2, bool active)
{
    const float inv_np = 1.0f / 49.0f;
    const float covh   = (49.0f / 48.0f) * 0.5f;

    float4 ring0[WIN], ring1[WIN];
    #pragma unroll
    for (int u = 0; u < WIN; ++u) {
        ring0[u] = make_float4(0.f, 0.f, 0.f, 0.f);
        ring1[u] = make_float4(0.f, 0.f, 0.f, 0.f);
    }
    float4 V0 = make_float4(0.f, 0.f, 0.f, 0.f);
    float4 V1 = make_float4(0.f, 0.f, 0.f, 0.f);

    float4 bufx[2][2], bufy[2][2];     // parity-indexed prefetch buffers
    double acc  = 0.0;
    float  esum = 0.f;

#define LOADROW(P, R) do {                                                    \
    const size_t o_ = (size_t)(R) * IMW;                                      \
    bufx[P][0] = *(const float4*)(Xp + o_);                                   \
    bufx[P][1] = *(const float4*)(Xp + o_ + 4);                               \
    bufy[P][0] = *(const float4*)(Yp + o_);                                   \
    bufy[P][1] = *(const float4*)(Yp + o_ + 4);                               \
} while (0)

    LOADROW(0, 0);                      // prologue

    #pragma unroll
    for (int u = 0; u < NROWS; ++u) {
        if (u + 1 < NROWS) LOADROW((u + 1) & 1, u + 1);

        {
            const float4 xa = bufx[u & 1][0], xb = bufx[u & 1][1];
            const float4 ya = bufy[u & 1][0], yb = bufy[u & 1][1];

            const float4 sa = make_float4(xa.x + ya.x, xa.y + ya.y,
                                          xa.z + ya.z, xa.w + ya.w);
            const float4 sb = make_float4(xb.x + yb.x, xb.y + yb.y,
                                          xb.z + yb.z, xb.w + yb.w);
            const float4 da = make_float4(xa.x - ya.x, xa.y - ya.y,
                                          xa.z - ya.z, xa.w - ya.w);
            const float4 db = make_float4(xb.x - yb.x, xb.y - yb.y,
                                          xb.z - yb.z, xb.w - yb.w);

            const float hs0 = ((sa.x + sa.y) + (sa.z + sa.w))
                            + ((sb.x + sb.y) + sb.z);
            const float hs1 = (hs0 - sa.x) + sb.w;
            const float hd0 = ((da.x + da.y) + (da.z + da.w))
                            + ((db.x + db.y) + db.z);
            const float hd1 = (hd0 - da.x) + db.w;
            const float hss0 = fmaf(sa.x, sa.x, fmaf(sa.y, sa.y,
                               fmaf(sa.z, sa.z, fmaf(sa.w, sa.w,
                               fmaf(sb.x, sb.x, fmaf(sb.y, sb.y,
                                    sb.z * sb.z))))));
            const float hss1 = fmaf(sb.w, sb.w, hss0 - sa.x * sa.x);
            const float hdd0 = fmaf(da.x, da.x, fmaf(da.y, da.y,
                               fmaf(da.z, da.z, fmaf(da.w, da.w,
                               fmaf(db.x, db.x, fmaf(db.y, db.y,
                                    db.z * db.z))))));
            const float hdd1 = fmaf(db.w, db.w, hdd0 - da.x * da.x);

            const int s = u % WIN;      // compile-time (loop fully unrolled)
            V0.x += hs0  - ring0[s].x;  V0.y += hd0  - ring0[s].y;
            V0.z += hss0 - ring0[s].z;  V0.w += hdd0 - ring0[s].w;
            V1.x += hs1  - ring1[s].x;  V1.y += hd1  - ring1[s].y;
            V1.z += hss1 - ring1[s].z;  V1.w += hdd1 - ring1[s].w;
            ring0[s] = make_float4(hs0, hd0, hss0, hdd0);
            ring1[s] = make_float4(hs1, hd1, hss1, hdd1);

            if (u >= WIN - 1 && active) {
                const float e0 = ssim_val(V0, C1, C2, inv_np, covh);
                const float e1 = ssim_val(V1, C1, C2, inv_np, covh);
                esum += e0 + e1;
            }
        }

        if (u % WIN == WIN - 1 || u == NROWS - 1) {   // compile-time
            acc += (double)esum;
            esum = 0.f;
        }
    }
#undef LOADROW
    return acc;
}

// 4 independent waves per block; only interaction is the final LDS reduce.
__global__ __launch_bounds__(256, 2) void ssim_stream(
    const float* __restrict__ X, const float* __restrict__ Y,
    const float* __restrict__ dr, double* __restrict__ partial)
{
    __shared__ double sred[WPB];

    const int tid  = threadIdx.x;
    const int lane = tid & 63;
    const int wv   = tid >> 6;

    const int task = blockIdx.x * WPB + wv;   // 0..10239
    const int tile = task % NCT;              // 4 block-waves = adjacent tiles
    const int band = (task / NCT) % NBANDS;
    const int b    = task / (NCT * NBANDS);

    const int r0 = band * BROWS;

    const int  ocol   = tile * 128 + 2 * lane;
    const int  cbase  = min(ocol, IMW - 8);
    const bool active = (ocol <= OWW - 2);

    const size_t ioff = (size_t)b * IMH * IMW + (size_t)r0 * IMW + cbase;
    const float* Xp = X + ioff;
    const float* Yp = Y + ioff;

    const float drv = dr[b];
    const float C1 = (0.01f * drv) * (0.01f * drv);
    const float C2 = (0.03f * drv) * (0.03f * drv);

    double acc;
    if (band < NBANDS - 1) {
        acc = band_loop<BROWS + WIN - 1>(Xp, Yp, C1, C2, active);   // 26 rows
    } else {
        acc = band_loop<IMH - (NBANDS - 1) * BROWS>(Xp, Yp, C1, C2, active); // 20
    }

    for (int off = 32; off > 0; off >>= 1)
        acc += __shfl_down(acc, off, 64);
    if (lane == 0) sred[wv] = acc;
    __syncthreads();
    if (tid == 0) {
        double t = 0.0;
        #pragma unroll
        for (int k = 0; k < WPB; ++k) t += sred[k];
        partial[blockIdx.x] = t;
    }
}

__global__ __launch_bounds__(512) void ssim_reduce(
    const double* __restrict__ partial, int n2, float* __restrict__ out)
{
    const double2* p2 = (const double2*)partial;
    double acc = 0.0;
    for (int i = threadIdx.x; i < n2; i += 512) {
        double2 v = p2[i];
        acc += v.x + v.y;
    }
    for (int off = 32; off > 0; off >>= 1)
        acc += __shfl_down(acc, off, 64);
    __shared__ double sred[8];
    if ((threadIdx.x & 63) == 0) sred[threadIdx.x >> 6] = acc;
    __syncthreads();
    if (threadIdx.x == 0) {
        double t = 0.0;
        #pragma unroll
        for (int k = 0; k < 8; ++k) t += sred[k];
        double denom = (double)NB * (double)OHH * (double)OWW;
        out[0] = (float)(t / denom);
    }
}

extern "C" void kernel_launch(void* const* d_in, const int* in_sizes, int n_in,
                              void* d_out, int out_size, void* d_ws, size_t ws_size,
                              hipStream_t stream) {
    const float* X  = (const float*)d_in[0];
    const float* Y  = (const float*)d_in[1];
    const float* dr = (const float*)d_in[2];
    // d_in[3] is w = ones/49; constant-folded in-kernel.
    double* partial = (double*)d_ws;   // 2560 * 8 B = 20 KB scratch

    ssim_stream<<<NBLK, 256, 0, stream>>>(X, Y, dr, partial);
    ssim_reduce<<<1, 512, 0, stream>>>(partial, NBLK / 2, (float*)d_out);
}

// Round 10
// 53.285 us; speedup vs baseline: 1.2770x; 1.0603x over previous
//
#include <hip/hip_runtime.h>

#define WIN    7
#define IMH    640
#define IMW    640
#define OHH    634            // IMH - WIN + 1
#define OWW    634
#define NB     64
#define NBANDS 32
#define BROWS  20             // 31*20 + 14 = 634 output rows
#define NCT    5              // column tiles of 128 output cols
#define NTASK  (NB * NBANDS * NCT)   // 10240 wave-tasks
#define WPB    4              // waves per block (256 threads)
#define NBLK   (NTASK / WPB)  // 2560 blocks -> 2560 partials

// SSIM from RAW 7x7 window sums (Ss,Sd,Sss,Sdd), using scale cancellation:
// each factor A1,A2,B1,B2 is evaluated scaled by 49^2; the ratio is unchanged.
// C1s/C2s = 2401*C1/C2.  covh = (49/48)*0.5 from the s/d transform.
__device__ __forceinline__ float ssim_val(const float4& V, float C1s, float C2s) {
    const float covh = (49.0f / 48.0f) * 0.5f;
    const float a  = V.x * V.x, b = V.y * V.y;
    const float pd = a - b, ps = a + b;
    const float A1 = fmaf(0.5f, pd, C1s);
    const float B1 = fmaf(0.5f, ps, C1s);
    const float t1 = V.z - V.w, t2 = V.z + V.w;
    const float w1 = fmaf(49.0f, t1, -pd);
    const float w2 = fmaf(49.0f, t2, -ps);
    const float A2 = fmaf(covh, w1, C2s);
    const float B2 = fmaf(covh, w2, C2s);
    return (A1 * A2) * __builtin_amdgcn_rcpf(B1 * B2);
}

// Fully-unrolled band loop with DEPTH-2 register prefetch (mod-3 buffers).
// NROWS compile-time => buffer slot (u%3), ring slot (u%7), DOSSIM all static
// (rule #20). Rows u+1,u+2 are in flight while row u computes (~480cy of
// compute between issue and wait), covering L2-miss/L3-hit latency.
template<int NROWS>
__device__ double band_loop(const float* __restrict__ Xp,
                            const float* __restrict__ Yp,
                            float C1s, float C2s, bool active)
{
    float4 ring0[WIN], ring1[WIN];
    #pragma unroll
    for (int u = 0; u < WIN; ++u) {
        ring0[u] = make_float4(0.f, 0.f, 0.f, 0.f);
        ring1[u] = make_float4(0.f, 0.f, 0.f, 0.f);
    }
    float4 V0 = make_float4(0.f, 0.f, 0.f, 0.f);
    float4 V1 = make_float4(0.f, 0.f, 0.f, 0.f);

    float4 bufx[3][2], bufy[3][2];     // mod-3 prefetch slots (all static idx)
    double acc  = 0.0;
    float  esum = 0.f;

#define LOADROW(P, R) do {                                                    \
    const size_t o_ = (size_t)(R) * IMW;                                      \
    bufx[P][0] = *(const float4*)(Xp + o_);                                   \
    bufx[P][1] = *(const float4*)(Xp + o_ + 4);                               \
    bufy[P][0] = *(const float4*)(Yp + o_);                                   \
    bufy[P][1] = *(const float4*)(Yp + o_ + 4);                               \
} while (0)

    LOADROW(0, 0);                      // prologue: rows 0,1 in flight
    LOADROW(1, 1);

    #pragma unroll
    for (int u = 0; u < NROWS; ++u) {
        if (u + 2 < NROWS) LOADROW((u + 2) % 3, u + 2);

        {
            const float4 xa = bufx[u % 3][0], xb = bufx[u % 3][1];
            const float4 ya = bufy[u % 3][0], yb = bufy[u % 3][1];

            const float4 sa = make_float4(xa.x + ya.x, xa.y + ya.y,
                                          xa.z + ya.z, xa.w + ya.w);
            const float4 sb = make_float4(xb.x + yb.x, xb.y + yb.y,
                                          xb.z + yb.z, xb.w + yb.w);
            const float4 da = make_float4(xa.x - ya.x, xa.y - ya.y,
                                          xa.z - ya.z, xa.w - ya.w);
            const float4 db = make_float4(xb.x - yb.x, xb.y - yb.y,
                                          xb.z - yb.z, xb.w - yb.w);

            const float hs0 = ((sa.x + sa.y) + (sa.z + sa.w))
                            + ((sb.x + sb.y) + sb.z);
            const float hs1 = (hs0 - sa.x) + sb.w;
            const float hd0 = ((da.x + da.y) + (da.z + da.w))
                            + ((db.x + db.y) + db.z);
            const float hd1 = (hd0 - da.x) + db.w;
            const float hss0 = fmaf(sa.x, sa.x, fmaf(sa.y, sa.y,
                               fmaf(sa.z, sa.z, fmaf(sa.w, sa.w,
                               fmaf(sb.x, sb.x, fmaf(sb.y, sb.y,
                                    sb.z * sb.z))))));
            const float hss1 = fmaf(sb.w, sb.w, hss0 - sa.x * sa.x);
            const float hdd0 = fmaf(da.x, da.x, fmaf(da.y, da.y,
                               fmaf(da.z, da.z, fmaf(da.w, da.w,
                               fmaf(db.x, db.x, fmaf(db.y, db.y,
                                    db.z * db.z))))));
            const float hdd1 = fmaf(db.w, db.w, hdd0 - da.x * da.x);

            const int s = u % WIN;      // compile-time (loop fully unrolled)
            V0.x += hs0  - ring0[s].x;  V0.y += hd0  - ring0[s].y;
            V0.z += hss0 - ring0[s].z;  V0.w += hdd0 - ring0[s].w;
            V1.x += hs1  - ring1[s].x;  V1.y += hd1  - ring1[s].y;
            V1.z += hss1 - ring1[s].z;  V1.w += hdd1 - ring1[s].w;
            ring0[s] = make_float4(hs0, hd0, hss0, hdd0);
            ring1[s] = make_float4(hs1, hd1, hss1, hdd1);

            if (u >= WIN - 1 && active) {
                const float e0 = ssim_val(V0, C1s, C2s);
                const float e1 = ssim_val(V1, C1s, C2s);
                esum += e0 + e1;
            }
        }

        if (u % WIN == WIN - 1 || u == NROWS - 1) {   // compile-time
            acc += (double)esum;
            esum = 0.f;
        }
    }
#undef LOADROW
    return acc;
}

// 4 independent waves per block; only interaction is the final LDS reduce.
__global__ __launch_bounds__(256, 2) void ssim_stream(
    const float* __restrict__ X, const float* __restrict__ Y,
    const float* __restrict__ dr, double* __restrict__ partial)
{
    __shared__ double sred[WPB];

    const int tid  = threadIdx.x;
    const int lane = tid & 63;
    const int wv   = tid >> 6;

    const int task = blockIdx.x * WPB + wv;   // 0..10239
    const int tile = task % NCT;              // 4 block-waves = adjacent tiles
    const int band = (task / NCT) % NBANDS;
    const int b    = task / (NCT * NBANDS);

    const int r0 = band * BROWS;

    const int  ocol   = tile * 128 + 2 * lane;
    const int  cbase  = min(ocol, IMW - 8);
    const bool active = (ocol <= OWW - 2);

    const size_t ioff = (size_t)b * IMH * IMW + (size_t)r0 * IMW + cbase;
    const float* Xp = X + ioff;
    const float* Yp = Y + ioff;

    const float drv = dr[b];
    const float C1s = 2401.0f * (0.01f * drv) * (0.01f * drv);
    const float C2s = 2401.0f * (0.03f * drv) * (0.03f * drv);

    double acc;
    if (band < NBANDS - 1) {
        acc = band_loop<BROWS + WIN - 1>(Xp, Yp, C1s, C2s, active);   // 26 rows
    } else {
        acc = band_loop<IMH - (NBANDS - 1) * BROWS>(Xp, Yp, C1s, C2s, active); // 20
    }

    for (int off = 32; off > 0; off >>= 1)
        acc += __shfl_down(acc, off, 64);
    if (lane == 0) sred[wv] = acc;
    __syncthreads();
    if (tid == 0) {
        double t = 0.0;
        #pragma unroll
        for (int k = 0; k < WPB; ++k) t += sred[k];
        partial[blockIdx.x] = t;
    }
}

__global__ __launch_bounds__(512) void ssim_reduce(
    const double* __restrict__ partial, int n2, float* __restrict__ out)
{
    const double2* p2 = (const double2*)partial;
    double acc = 0.0;
    for (int i = threadIdx.x; i < n2; i += 512) {
        double2 v = p2[i];
        acc += v.x + v.y;
    }
    for (int off = 32; off > 0; off >>= 1)
        acc += __shfl_down(acc, off, 64);
    __shared__ double sred[8];
    if ((threadIdx.x & 63) == 0) sred[threadIdx.x >> 6] = acc;
    __syncthreads();
    if (threadIdx.x == 0) {
        double t = 0.0;
        #pragma unroll
        for (int k = 0; k < 8; ++k) t += sred[k];
        double denom = (double)NB * (double)OHH * (double)OWW;
        out[0] = (float)(t / denom);
    }
}

extern "C" void kernel_launch(void* const* d_in, const int* in_sizes, int n_in,
                              void* d_out, int out_size, void* d_ws, size_t ws_size,
                              hipStream_t stream) {
    const float* X  = (const float*)d_in[0];
    const float* Y  = (const float*)d_in[1];
    const float* dr = (const float*)d_in[2];
    // d_in[3] is w = ones/49; constant-folded in-kernel.
    double* partial = (double*)d_ws;   // 2560 * 8 B = 20 KB scratch

    ssim_stream<<<NBLK, 256, 0, stream>>>(X, Y, dr, partial);
    ssim_reduce<<<1, 512, 0, stream>>>(partial, NBLK / 2, (float*)d_out);
}